// Round 3
// baseline (543.019 us; speedup 1.0000x reference)
//
#include <hip/hip_runtime.h>
#include <math.h>

#define NR   8192
#define DIM  256
#define QBLK 32

using bf16x8 = __attribute__((ext_vector_type(8))) short;
using f32x4  = __attribute__((ext_vector_type(4))) float;
using s4v    = __attribute__((ext_vector_type(4))) short;

// LDS plane offsets (in shorts). Row-major K planes: [32][264] (528B stride, pad
// so 16 lanes reading stride-528B rows hit 8 distinct banks = 2-way = free).
// Transposed plane: [256][40] (80B stride, same trick). pbuf: [16][40] per wave.
#define KH0 0
#define KH1 8448
#define KL0 16896
#define KL1 25344
#define MT0 33792
#define MT1 44032
#define PBO 54272
#define LDS_SHORTS 56832   // 113664 bytes

__device__ __forceinline__ short f2bf(float x){
  union{float f; unsigned u;} v; v.f = x;
  unsigned r = v.u + 0x7fffu + ((v.u >> 16) & 1u);
  return (short)(r >> 16);
}
__device__ __forceinline__ float bf2f(short s){
  union{unsigned u; float f;} v; v.u = ((unsigned)(unsigned short)s) << 16;
  return v.f;
}

__launch_bounds__(256, 1)
__global__ void attn_gate_kernel(const float* __restrict__ Mp, const float* __restrict__ Np,
                                 const float* __restrict__ gw, const float* __restrict__ gwb,
                                 const float* __restrict__ gb, float* __restrict__ out)
{
  extern __shared__ short S_[];
  const int tid  = threadIdx.x;
  const int w    = tid >> 6;
  const int lane = tid & 63;
  const int g    = lane >> 4;      // 4-lane-group id (k-group)
  const int li   = lane & 15;      // position within 16
  const int qsub = w & 1;          // which 16 q-rows
  const int par  = w >> 1;         // kv tile parity
  const int qb   = blockIdx.x * QBLK;

  short* khp = S_ + (par ? KH1 : KH0);
  short* klp = S_ + (par ? KL1 : KL0);
  short* mtp = S_ + (par ? MT1 : MT0);
  short* pb  = S_ + PBO + w * 640;

  // ---- Q fragments (hi/lo split), row = qb + qsub*16 + li ----
  bf16x8 qh[8], ql[8];
  {
    const float* qrow = Np + (size_t)(qb + qsub*16 + li) * DIM;
    #pragma unroll
    for (int kk = 0; kk < 8; ++kk){
      const int d0 = kk*32 + g*8;
      #pragma unroll
      for (int j = 0; j < 8; ++j){
        float f = qrow[d0 + j];
        short h = f2bf(f);
        qh[kk][j] = h;
        ql[kk][j] = f2bf(f - bf2f(h));
      }
    }
  }

  f32x4 o[16];
  #pragma unroll
  for (int nf = 0; nf < 16; ++nf){ f32x4 z = {0.f,0.f,0.f,0.f}; o[nf] = z; }
  float m0[4], l0[4];
  #pragma unroll
  for (int i = 0; i < 4; ++i){ m0[i] = -1e30f; l0[i] = 0.0f; }

  const int NSS = NR / 64;
  for (int ss = 0; ss < NSS; ++ss){
    // ---- stage 64 rows of M: hi+lo row-major, hi transposed ----
    {
      const int r  = tid >> 2;          // 0..63
      const int cb = (tid & 3) << 6;    // 0,64,128,192
      const int p  = r >> 5;
      const int rr = r & 31;
      short* kh = S_ + (p ? KH1 : KH0) + rr*264 + cb;
      short* kl = S_ + (p ? KL1 : KL0) + rr*264 + cb;
      short* mt = S_ + (p ? MT1 : MT0) + rr;
      const float* src = Mp + (size_t)(ss*64 + r) * DIM + cb;
      #pragma unroll
      for (int c = 0; c < 64; c += 4){
        const float4 v = *(const float4*)(src + c);
        float fv[4] = {v.x, v.y, v.z, v.w};
        short h[4], lo[4];
        #pragma unroll
        for (int j = 0; j < 4; ++j){
          h[j]  = f2bf(fv[j]);
          lo[j] = f2bf(fv[j] - bf2f(h[j]));
          mt[(cb + c + j) * 40] = h[j];
        }
        s4v hv = {h[0], h[1], h[2], h[3]};
        s4v lv = {lo[0], lo[1], lo[2], lo[3]};
        *(s4v*)(kh + c) = hv;
        *(s4v*)(kl + c) = lv;
      }
    }
    __syncthreads();

    // ---- QK^T (hi/lo split): S = Qh*Kh + Qh*Kl + Ql*Kh ----
    f32x4 sa[2];
    { f32x4 z = {0.f,0.f,0.f,0.f}; sa[0] = z; sa[1] = z; }
    #pragma unroll
    for (int kk = 0; kk < 8; ++kk){
      #pragma unroll
      for (int n = 0; n < 2; ++n){
        const int a = (n*16 + li)*264 + kk*32 + g*8;
        bf16x8 bh = *(const bf16x8*)(khp + a);
        bf16x8 bl = *(const bf16x8*)(klp + a);
        sa[n] = __builtin_amdgcn_mfma_f32_16x16x32_bf16(qh[kk], bh, sa[n], 0, 0, 0);
        sa[n] = __builtin_amdgcn_mfma_f32_16x16x32_bf16(qh[kk], bl, sa[n], 0, 0, 0);
        sa[n] = __builtin_amdgcn_mfma_f32_16x16x32_bf16(ql[kk], bh, sa[n], 0, 0, 0);
      }
    }

    // ---- online softmax ----
    const int kvb   = ss*64 + par*32;
    const int growb = qb + qsub*16 + g*4;
    float s_[2][4];
    #pragma unroll
    for (int n = 0; n < 2; ++n)
      #pragma unroll
      for (int i = 0; i < 4; ++i){
        float sv = sa[n][i];
        if (kvb + n*16 + li == growb + i) sv = 0.0f;   // zeroed diagonal
        s_[n][i] = sv;
      }
    float mn[4], sc[4], ps[4];
    bool need = false;
    #pragma unroll
    for (int i = 0; i < 4; ++i){
      float t = fmaxf(s_[0][i], s_[1][i]);
      t = fmaxf(t, __shfl_xor(t, 1));
      t = fmaxf(t, __shfl_xor(t, 2));
      t = fmaxf(t, __shfl_xor(t, 4));
      t = fmaxf(t, __shfl_xor(t, 8));
      mn[i] = fmaxf(m0[i], t);
      sc[i] = __expf(m0[i] - mn[i]);
      need |= (mn[i] != m0[i]);
      m0[i] = mn[i];
    }
    #pragma unroll
    for (int i = 0; i < 4; ++i) ps[i] = 0.0f;
    #pragma unroll
    for (int n = 0; n < 2; ++n)
      #pragma unroll
      for (int i = 0; i < 4; ++i){
        float p = __expf(s_[n][i] - mn[i]);
        ps[i] += p;
        pb[(g*4 + i)*40 + n*16 + li] = f2bf(p);
      }
    #pragma unroll
    for (int i = 0; i < 4; ++i){
      float t = ps[i];
      t += __shfl_xor(t, 1);
      t += __shfl_xor(t, 2);
      t += __shfl_xor(t, 4);
      t += __shfl_xor(t, 8);
      l0[i] = l0[i]*sc[i] + t;
    }
    if (__any((int)need)){
      #pragma unroll
      for (int nf = 0; nf < 16; ++nf)
        #pragma unroll
        for (int i = 0; i < 4; ++i) o[nf][i] *= sc[i];
    }

    // ---- PV: O += P * Mtile  (P from pbuf, M from transposed plane) ----
    bf16x8 pa = *(const bf16x8*)(pb + li*40 + g*8);
    #pragma unroll
    for (int nf = 0; nf < 16; ++nf){
      bf16x8 bv = *(const bf16x8*)(mtp + (nf*16 + li)*40 + g*8);
      o[nf] = __builtin_amdgcn_mfma_f32_16x16x32_bf16(pa, bv, o[nf], 0, 0, 0);
    }
    __syncthreads();
  }

  // ---- merge the two KV-parity partials (flash combine) ----
  float* dump = (float*)S_;
  if (par == 1){
    float* dp = dump + (size_t)(qsub*64 + lane) * 72;
    #pragma unroll
    for (int i = 0; i < 4; ++i){ dp[i] = m0[i]; dp[4+i] = l0[i]; }
    #pragma unroll
    for (int nf = 0; nf < 16; ++nf)
      #pragma unroll
      for (int i = 0; i < 4; ++i) dp[8 + nf*4 + i] = o[nf][i];
  }
  __syncthreads();
  if (par == 0){
    const float* dp = dump + (size_t)(qsub*64 + lane) * 72;
    float a[4], b[4];
    #pragma unroll
    for (int i = 0; i < 4; ++i){
      float mb = dp[i], lb = dp[4+i];
      float mm = fmaxf(m0[i], mb);
      a[i] = __expf(m0[i] - mm);
      b[i] = __expf(mb - mm);
      l0[i] = l0[i]*a[i] + lb*b[i];
    }
    #pragma unroll
    for (int nf = 0; nf < 16; ++nf)
      #pragma unroll
      for (int i = 0; i < 4; ++i)
        o[nf][i] = o[nf][i]*a[i] + dp[8 + nf*4 + i]*b[i];

    float inv[4];
    #pragma unroll
    for (int i = 0; i < 4; ++i) inv[i] = 1.0f / l0[i];
    #pragma unroll
    for (int nf = 0; nf < 16; ++nf)
      #pragma unroll
      for (int i = 0; i < 4; ++i) o[nf][i] *= inv[i];

    // ---- gate: g = sigmoid(O·w + b1 + b2), out = O*g + N*(1-g) ----
    float t[4] = {0.f, 0.f, 0.f, 0.f};
    #pragma unroll
    for (int nf = 0; nf < 16; ++nf){
      float wv = gw[nf*16 + li];
      #pragma unroll
      for (int i = 0; i < 4; ++i) t[i] += o[nf][i] * wv;
    }
    const float bias = gwb[0] + gb[0];
    float gt[4];
    #pragma unroll
    for (int i = 0; i < 4; ++i){
      float x = t[i];
      x += __shfl_xor(x, 1);
      x += __shfl_xor(x, 2);
      x += __shfl_xor(x, 4);
      x += __shfl_xor(x, 8);
      gt[i] = 1.0f / (1.0f + __expf(-(x + bias)));
    }
    #pragma unroll
    for (int i = 0; i < 4; ++i){
      const int grow = qb + qsub*16 + g*4 + i;
      const float* nrow = Np + (size_t)grow * DIM;
      float* orow = out + (size_t)grow * DIM;
      #pragma unroll
      for (int nf = 0; nf < 16; ++nf){
        const int col = nf*16 + li;
        float nv = nrow[col];
        orow[col] = o[nf][i]*gt[i] + nv*(1.0f - gt[i]);
      }
    }
  }
}

extern "C" void kernel_launch(void* const* d_in, const int* in_sizes, int n_in,
                              void* d_out, int out_size, void* d_ws, size_t ws_size,
                              hipStream_t stream)
{
  const float* Mp  = (const float*)d_in[0];
  const float* Np  = (const float*)d_in[1];
  const float* gw  = (const float*)d_in[2];
  const float* gwb = (const float*)d_in[3];
  const float* gb  = (const float*)d_in[4];
  float* out = (float*)d_out;

  const size_t shmem = (size_t)LDS_SHORTS * sizeof(short);  // 113664 B
  hipFuncSetAttribute((const void*)attn_gate_kernel,
                      hipFuncAttributeMaxDynamicSharedMemorySize, (int)shmem);
  attn_gate_kernel<<<NR / QBLK, 256, shmem, stream>>>(Mp, Np, gw, gwb, gb, out);
}

// Round 4
// 352.337 us; speedup vs baseline: 1.5412x; 1.5412x over previous
//
#include <hip/hip_runtime.h>
#include <math.h>

#define NR   8192
#define DIM  256
#define QBLK 32

using bf16x8 = __attribute__((ext_vector_type(8))) short;
using f32x4  = __attribute__((ext_vector_type(4))) float;
using s4v    = __attribute__((ext_vector_type(4))) short;
using s8v    = __attribute__((ext_vector_type(8))) short;

__device__ __forceinline__ short f2bf(float x){
  union{float f; unsigned u;} v; v.f = x;
  unsigned r = v.u + 0x7fffu + ((v.u >> 16) & 1u);
  return (short)(r >> 16);
}
__device__ __forceinline__ float bf2f(short s){
  union{unsigned u; float f;} v; v.u = ((unsigned)(unsigned short)s) << 16;
  return v.f;
}

// ============================ V1: ws-precomputed path ============================
// ws layout (shorts), per superstep ss (64 kv rows), region of 49152 shorts:
//   KH: +0      + p*8192 + (kk*2+n)*512 + l*8 + j  = hi(M[ss*64+p*32+n*16+(l&15)][kk*32+(l>>4)*8+j])
//   KL: +16384  (same addressing, lo plane)
//   VT: +32768  + p*8192 + nf*512     + l*8 + j  = hi(M[ss*64+p*32+(l>>4)*8+j][nf*16+(l&15)])
// Fragment-major: every MFMA B-fragment is 64 lanes x 16B contiguous -> linear
// global_load_lds staging and conflict-free ds_read_b128 (addr = base + lane*16).
#define SS_SHORTS 49152
#define KH_OFF 0
#define KL_OFF 16384
#define VT_OFF 32768
#define PB_OFF 49152
#define LDS1_SHORTS (49152 + 2560)       // 51712 shorts = 103424 bytes
#define WS_BYTES_NEEDED (128u * 49152u * 2u)   // 12,582,912

__device__ __forceinline__ void dma16(const short* g, short* l){
  __builtin_amdgcn_global_load_lds(
      (const __attribute__((address_space(1))) unsigned int*)g,
      (__attribute__((address_space(3))) unsigned int*)l, 16, 0, 0);
}

__launch_bounds__(256)
__global__ void precompute_ws(const float* __restrict__ Mp, short* __restrict__ ws)
{
  const int tid = threadIdx.x;
  const int bx  = blockIdx.x;        // 128 ss * 24 subblocks
  const int ss  = bx / 24;
  const int sub = bx % 24;
  const int fi  = sub*256 + tid;     // 0..6143 fragment-lane id within ss
  const int plane = fi >> 11;        // 0=KH 1=KL 2=VT
  const int rest  = fi & 2047;
  const int p   = rest >> 10;
  const int cl  = rest & 1023;
  const int ch  = cl >> 6;
  const int l   = cl & 63;
  const int li  = l & 15, g = l >> 4;

  short v[8];
  if (plane < 2){
    const int kk = ch >> 1, n = ch & 1;
    const int row = ss*64 + p*32 + n*16 + li;
    const int d0  = kk*32 + g*8;
    const float* src = Mp + (size_t)row*DIM + d0;
    #pragma unroll
    for (int j = 0; j < 8; ++j){
      float fv = src[j];
      short h = f2bf(fv);
      v[j] = (plane == 0) ? h : f2bf(fv - bf2f(h));
    }
  } else {
    const int nf = ch;
    const int d  = nf*16 + li;
    #pragma unroll
    for (int j = 0; j < 8; ++j){
      const int row = ss*64 + p*32 + g*8 + j;
      v[j] = f2bf(Mp[(size_t)row*DIM + d]);
    }
  }
  s8v ov = {v[0],v[1],v[2],v[3],v[4],v[5],v[6],v[7]};
  *(s8v*)(ws + (size_t)ss*SS_SHORTS + plane*16384 + p*8192 + ch*512 + l*8) = ov;
}

__launch_bounds__(256, 1)
__global__ void attn_gate_v1(const float* __restrict__ Np,
                             const float* __restrict__ gw, const float* __restrict__ gwb,
                             const float* __restrict__ gb,
                             const short* __restrict__ ws, float* __restrict__ out)
{
  extern __shared__ short S_[];
  const int tid  = threadIdx.x;
  const int w    = tid >> 6;
  const int lane = tid & 63;
  const int g    = lane >> 4;
  const int li   = lane & 15;
  const int qsub = w & 1;
  const int par  = w >> 1;
  const int qb   = blockIdx.x * QBLK;
  short* pb = S_ + PB_OFF + w * 640;

  // ---- Q fragments (hi/lo split) from N, once per block ----
  bf16x8 qh[8], ql[8];
  {
    const float* qrow = Np + (size_t)(qb + qsub*16 + li) * DIM;
    #pragma unroll
    for (int kk = 0; kk < 8; ++kk){
      const int d0 = kk*32 + g*8;
      #pragma unroll
      for (int j = 0; j < 8; ++j){
        float f = qrow[d0 + j];
        short h = f2bf(f);
        qh[kk][j] = h;
        ql[kk][j] = f2bf(f - bf2f(h));
      }
    }
  }

  f32x4 o[16];
  #pragma unroll
  for (int nf = 0; nf < 16; ++nf){ f32x4 z = {0.f,0.f,0.f,0.f}; o[nf] = z; }
  float m0[4], l0[4];
  #pragma unroll
  for (int i = 0; i < 4; ++i){ m0[i] = -1e30f; l0[i] = 0.0f; }

  // ---- prologue: DMA KH+KL of ss=0 ----
  #pragma unroll
  for (int i = 0; i < 16; ++i){
    const int X = (w*16 + i) * 512;
    dma16(ws + X + lane*8, S_ + X);
  }
  __syncthreads();

  for (int ss = 0; ss < 128; ++ss){
    const size_t ssb = (size_t)ss * SS_SHORTS;

    // phase 1: issue VT(ss) DMA, compute QK^T + softmax from KH/KL
    #pragma unroll
    for (int i = 0; i < 8; ++i){
      const int X = VT_OFF + (w*8 + i) * 512;
      dma16(ws + ssb + X + lane*8, S_ + X);
    }

    f32x4 sa[2];
    { f32x4 z = {0.f,0.f,0.f,0.f}; sa[0] = z; sa[1] = z; }
    #pragma unroll
    for (int kk = 0; kk < 8; ++kk){
      #pragma unroll
      for (int n = 0; n < 2; ++n){
        const int co = par*8192 + (kk*2 + n)*512 + lane*8;
        bf16x8 bh = *(const bf16x8*)(S_ + KH_OFF + co);
        bf16x8 bl = *(const bf16x8*)(S_ + KL_OFF + co);
        sa[n] = __builtin_amdgcn_mfma_f32_16x16x32_bf16(qh[kk], bh, sa[n], 0, 0, 0);
        sa[n] = __builtin_amdgcn_mfma_f32_16x16x32_bf16(qh[kk], bl, sa[n], 0, 0, 0);
        sa[n] = __builtin_amdgcn_mfma_f32_16x16x32_bf16(ql[kk], bh, sa[n], 0, 0, 0);
      }
    }

    const int kvb   = ss*64 + par*32;
    const int growb = qb + qsub*16 + g*4;
    float s_[2][4];
    #pragma unroll
    for (int n = 0; n < 2; ++n)
      #pragma unroll
      for (int i = 0; i < 4; ++i){
        float sv = sa[n][i];
        if (kvb + n*16 + li == growb + i) sv = 0.0f;
        s_[n][i] = sv;
      }
    float mn[4], sc[4], ps[4];
    bool need = false;
    #pragma unroll
    for (int i = 0; i < 4; ++i){
      float t = fmaxf(s_[0][i], s_[1][i]);
      t = fmaxf(t, __shfl_xor(t, 1));
      t = fmaxf(t, __shfl_xor(t, 2));
      t = fmaxf(t, __shfl_xor(t, 4));
      t = fmaxf(t, __shfl_xor(t, 8));
      mn[i] = fmaxf(m0[i], t);
      sc[i] = __expf(m0[i] - mn[i]);
      need |= (mn[i] != m0[i]);
      m0[i] = mn[i];
    }
    #pragma unroll
    for (int i = 0; i < 4; ++i) ps[i] = 0.0f;
    #pragma unroll
    for (int n = 0; n < 2; ++n)
      #pragma unroll
      for (int i = 0; i < 4; ++i){
        float p = __expf(s_[n][i] - mn[i]);
        ps[i] += p;
        pb[(g*4 + i)*40 + n*16 + li] = f2bf(p);
      }
    #pragma unroll
    for (int i = 0; i < 4; ++i){
      float t = ps[i];
      t += __shfl_xor(t, 1);
      t += __shfl_xor(t, 2);
      t += __shfl_xor(t, 4);
      t += __shfl_xor(t, 8);
      l0[i] = l0[i]*sc[i] + t;
    }
    if (__any((int)need)){
      #pragma unroll
      for (int nf = 0; nf < 16; ++nf)
        #pragma unroll
        for (int i = 0; i < 4; ++i) o[nf][i] *= sc[i];
    }
    __syncthreads();   // VT arrived, pbuf visible, KH/KL reads done

    // phase 2: issue KH/KL(ss+1) DMA, compute PV from VT
    if (ss < 127){
      #pragma unroll
      for (int i = 0; i < 16; ++i){
        const int X = (w*16 + i) * 512;
        dma16(ws + ssb + SS_SHORTS + X + lane*8, S_ + X);
      }
    }
    bf16x8 pa = *(const bf16x8*)(pb + li*40 + g*8);
    #pragma unroll
    for (int nf = 0; nf < 16; ++nf){
      bf16x8 bv = *(const bf16x8*)(S_ + VT_OFF + par*8192 + nf*512 + lane*8);
      o[nf] = __builtin_amdgcn_mfma_f32_16x16x32_bf16(pa, bv, o[nf], 0, 0, 0);
    }
    __syncthreads();   // KH/KL(ss+1) arrived, VT reads done
  }

  // ---- merge kv-parity partials + gate + store (par 0 writes) ----
  float* dump = (float*)S_;
  if (par == 1){
    float* dp = dump + (size_t)(qsub*64 + lane) * 72;
    #pragma unroll
    for (int i = 0; i < 4; ++i){ dp[i] = m0[i]; dp[4+i] = l0[i]; }
    #pragma unroll
    for (int nf = 0; nf < 16; ++nf)
      #pragma unroll
      for (int i = 0; i < 4; ++i) dp[8 + nf*4 + i] = o[nf][i];
  }
  __syncthreads();
  if (par == 0){
    const float* dp = dump + (size_t)(qsub*64 + lane) * 72;
    float a[4], b[4];
    #pragma unroll
    for (int i = 0; i < 4; ++i){
      float mb = dp[i], lb = dp[4+i];
      float mm = fmaxf(m0[i], mb);
      a[i] = __expf(m0[i] - mm);
      b[i] = __expf(mb - mm);
      l0[i] = l0[i]*a[i] + lb*b[i];
    }
    #pragma unroll
    for (int nf = 0; nf < 16; ++nf)
      #pragma unroll
      for (int i = 0; i < 4; ++i)
        o[nf][i] = o[nf][i]*a[i] + dp[8 + nf*4 + i]*b[i];

    float inv[4];
    #pragma unroll
    for (int i = 0; i < 4; ++i) inv[i] = 1.0f / l0[i];
    #pragma unroll
    for (int nf = 0; nf < 16; ++nf)
      #pragma unroll
      for (int i = 0; i < 4; ++i) o[nf][i] *= inv[i];

    float t[4] = {0.f, 0.f, 0.f, 0.f};
    #pragma unroll
    for (int nf = 0; nf < 16; ++nf){
      float wv = gw[nf*16 + li];
      #pragma unroll
      for (int i = 0; i < 4; ++i) t[i] += o[nf][i] * wv;
    }
    const float bias = gwb[0] + gb[0];
    float gt[4];
    #pragma unroll
    for (int i = 0; i < 4; ++i){
      float x = t[i];
      x += __shfl_xor(x, 1);
      x += __shfl_xor(x, 2);
      x += __shfl_xor(x, 4);
      x += __shfl_xor(x, 8);
      gt[i] = 1.0f / (1.0f + __expf(-(x + bias)));
    }
    #pragma unroll
    for (int i = 0; i < 4; ++i){
      const int grow = qb + qsub*16 + g*4 + i;
      const float* nrow = Np + (size_t)grow * DIM;
      float* orow = out + (size_t)grow * DIM;
      #pragma unroll
      for (int nf = 0; nf < 16; ++nf){
        const int col = nf*16 + li;
        float nv = nrow[col];
        orow[col] = o[nf][i]*gt[i] + nv*(1.0f - gt[i]);
      }
    }
  }
}

// ============================ V0: fallback (round-3 kernel) ============================
#define KH0 0
#define KH1 8448
#define KL0 16896
#define KL1 25344
#define MT0 33792
#define MT1 44032
#define PBO 54272
#define LDS0_SHORTS 56832

__launch_bounds__(256, 1)
__global__ void attn_gate_v0(const float* __restrict__ Mp, const float* __restrict__ Np,
                             const float* __restrict__ gw, const float* __restrict__ gwb,
                             const float* __restrict__ gb, float* __restrict__ out)
{
  extern __shared__ short S_[];
  const int tid  = threadIdx.x;
  const int w    = tid >> 6;
  const int lane = tid & 63;
  const int g    = lane >> 4;
  const int li   = lane & 15;
  const int qsub = w & 1;
  const int par  = w >> 1;
  const int qb   = blockIdx.x * QBLK;

  short* khp = S_ + (par ? KH1 : KH0);
  short* klp = S_ + (par ? KL1 : KL0);
  short* mtp = S_ + (par ? MT1 : MT0);
  short* pb  = S_ + PBO + w * 640;

  bf16x8 qh[8], ql[8];
  {
    const float* qrow = Np + (size_t)(qb + qsub*16 + li) * DIM;
    #pragma unroll
    for (int kk = 0; kk < 8; ++kk){
      const int d0 = kk*32 + g*8;
      #pragma unroll
      for (int j = 0; j < 8; ++j){
        float f = qrow[d0 + j];
        short h = f2bf(f);
        qh[kk][j] = h;
        ql[kk][j] = f2bf(f - bf2f(h));
      }
    }
  }

  f32x4 o[16];
  #pragma unroll
  for (int nf = 0; nf < 16; ++nf){ f32x4 z = {0.f,0.f,0.f,0.f}; o[nf] = z; }
  float m0[4], l0[4];
  #pragma unroll
  for (int i = 0; i < 4; ++i){ m0[i] = -1e30f; l0[i] = 0.0f; }

  const int NSS = NR / 64;
  for (int ss = 0; ss < NSS; ++ss){
    {
      const int r  = tid >> 2;
      const int cb = (tid & 3) << 6;
      const int p  = r >> 5;
      const int rr = r & 31;
      short* kh = S_ + (p ? KH1 : KH0) + rr*264 + cb;
      short* kl = S_ + (p ? KL1 : KL0) + rr*264 + cb;
      short* mt = S_ + (p ? MT1 : MT0) + rr;
      const float* src = Mp + (size_t)(ss*64 + r) * DIM + cb;
      #pragma unroll
      for (int c = 0; c < 64; c += 4){
        const float4 v = *(const float4*)(src + c);
        float fv[4] = {v.x, v.y, v.z, v.w};
        short h[4], lo[4];
        #pragma unroll
        for (int j = 0; j < 4; ++j){
          h[j]  = f2bf(fv[j]);
          lo[j] = f2bf(fv[j] - bf2f(h[j]));
          mt[(cb + c + j) * 40] = h[j];
        }
        s4v hv = {h[0], h[1], h[2], h[3]};
        s4v lv = {lo[0], lo[1], lo[2], lo[3]};
        *(s4v*)(kh + c) = hv;
        *(s4v*)(kl + c) = lv;
      }
    }
    __syncthreads();

    f32x4 sa[2];
    { f32x4 z = {0.f,0.f,0.f,0.f}; sa[0] = z; sa[1] = z; }
    #pragma unroll
    for (int kk = 0; kk < 8; ++kk){
      #pragma unroll
      for (int n = 0; n < 2; ++n){
        const int a = (n*16 + li)*264 + kk*32 + g*8;
        bf16x8 bh = *(const bf16x8*)(khp + a);
        bf16x8 bl = *(const bf16x8*)(klp + a);
        sa[n] = __builtin_amdgcn_mfma_f32_16x16x32_bf16(qh[kk], bh, sa[n], 0, 0, 0);
        sa[n] = __builtin_amdgcn_mfma_f32_16x16x32_bf16(qh[kk], bl, sa[n], 0, 0, 0);
        sa[n] = __builtin_amdgcn_mfma_f32_16x16x32_bf16(ql[kk], bh, sa[n], 0, 0, 0);
      }
    }

    const int kvb   = ss*64 + par*32;
    const int growb = qb + qsub*16 + g*4;
    float s_[2][4];
    #pragma unroll
    for (int n = 0; n < 2; ++n)
      #pragma unroll
      for (int i = 0; i < 4; ++i){
        float sv = sa[n][i];
        if (kvb + n*16 + li == growb + i) sv = 0.0f;
        s_[n][i] = sv;
      }
    float mn[4], sc[4], ps[4];
    bool need = false;
    #pragma unroll
    for (int i = 0; i < 4; ++i){
      float t = fmaxf(s_[0][i], s_[1][i]);
      t = fmaxf(t, __shfl_xor(t, 1));
      t = fmaxf(t, __shfl_xor(t, 2));
      t = fmaxf(t, __shfl_xor(t, 4));
      t = fmaxf(t, __shfl_xor(t, 8));
      mn[i] = fmaxf(m0[i], t);
      sc[i] = __expf(m0[i] - mn[i]);
      need |= (mn[i] != m0[i]);
      m0[i] = mn[i];
    }
    #pragma unroll
    for (int i = 0; i < 4; ++i) ps[i] = 0.0f;
    #pragma unroll
    for (int n = 0; n < 2; ++n)
      #pragma unroll
      for (int i = 0; i < 4; ++i){
        float p = __expf(s_[n][i] - mn[i]);
        ps[i] += p;
        pb[(g*4 + i)*40 + n*16 + li] = f2bf(p);
      }
    #pragma unroll
    for (int i = 0; i < 4; ++i){
      float t = ps[i];
      t += __shfl_xor(t, 1);
      t += __shfl_xor(t, 2);
      t += __shfl_xor(t, 4);
      t += __shfl_xor(t, 8);
      l0[i] = l0[i]*sc[i] + t;
    }
    if (__any((int)need)){
      #pragma unroll
      for (int nf = 0; nf < 16; ++nf)
        #pragma unroll
        for (int i = 0; i < 4; ++i) o[nf][i] *= sc[i];
    }

    bf16x8 pa = *(const bf16x8*)(pb + li*40 + g*8);
    #pragma unroll
    for (int nf = 0; nf < 16; ++nf){
      bf16x8 bv = *(const bf16x8*)(mtp + (nf*16 + li)*40 + g*8);
      o[nf] = __builtin_amdgcn_mfma_f32_16x16x32_bf16(pa, bv, o[nf], 0, 0, 0);
    }
    __syncthreads();
  }

  float* dump = (float*)S_;
  if (par == 1){
    float* dp = dump + (size_t)(qsub*64 + lane) * 72;
    #pragma unroll
    for (int i = 0; i < 4; ++i){ dp[i] = m0[i]; dp[4+i] = l0[i]; }
    #pragma unroll
    for (int nf = 0; nf < 16; ++nf)
      #pragma unroll
      for (int i = 0; i < 4; ++i) dp[8 + nf*4 + i] = o[nf][i];
  }
  __syncthreads();
  if (par == 0){
    const float* dp = dump + (size_t)(qsub*64 + lane) * 72;
    float a[4], b[4];
    #pragma unroll
    for (int i = 0; i < 4; ++i){
      float mb = dp[i], lb = dp[4+i];
      float mm = fmaxf(m0[i], mb);
      a[i] = __expf(m0[i] - mm);
      b[i] = __expf(mb - mm);
      l0[i] = l0[i]*a[i] + lb*b[i];
    }
    #pragma unroll
    for (int nf = 0; nf < 16; ++nf)
      #pragma unroll
      for (int i = 0; i < 4; ++i)
        o[nf][i] = o[nf][i]*a[i] + dp[8 + nf*4 + i]*b[i];

    float inv[4];
    #pragma unroll
    for (int i = 0; i < 4; ++i) inv[i] = 1.0f / l0[i];
    #pragma unroll
    for (int nf = 0; nf < 16; ++nf)
      #pragma unroll
      for (int i = 0; i < 4; ++i) o[nf][i] *= inv[i];

    float t[4] = {0.f, 0.f, 0.f, 0.f};
    #pragma unroll
    for (int nf = 0; nf < 16; ++nf){
      float wv = gw[nf*16 + li];
      #pragma unroll
      for (int i = 0; i < 4; ++i) t[i] += o[nf][i] * wv;
    }
    const float bias = gwb[0] + gb[0];
    float gt[4];
    #pragma unroll
    for (int i = 0; i < 4; ++i){
      float x = t[i];
      x += __shfl_xor(x, 1);
      x += __shfl_xor(x, 2);
      x += __shfl_xor(x, 4);
      x += __shfl_xor(x, 8);
      gt[i] = 1.0f / (1.0f + __expf(-(x + bias)));
    }
    #pragma unroll
    for (int i = 0; i < 4; ++i){
      const int grow = qb + qsub*16 + g*4 + i;
      const float* nrow = Np + (size_t)grow * DIM;
      float* orow = out + (size_t)grow * DIM;
      #pragma unroll
      for (int nf = 0; nf < 16; ++nf){
        const int col = nf*16 + li;
        float nv = nrow[col];
        orow[col] = o[nf][i]*gt[i] + nv*(1.0f - gt[i]);
      }
    }
  }
}

extern "C" void kernel_launch(void* const* d_in, const int* in_sizes, int n_in,
                              void* d_out, int out_size, void* d_ws, size_t ws_size,
                              hipStream_t stream)
{
  const float* Mp  = (const float*)d_in[0];
  const float* Np  = (const float*)d_in[1];
  const float* gw  = (const float*)d_in[2];
  const float* gwb = (const float*)d_in[3];
  const float* gb  = (const float*)d_in[4];
  float* out = (float*)d_out;

  if (ws_size >= (size_t)WS_BYTES_NEEDED){
    short* ws = (short*)d_ws;
    precompute_ws<<<128*24, 256, 0, stream>>>(Mp, ws);
    const size_t shmem = (size_t)LDS1_SHORTS * sizeof(short);  // 103424 B
    hipFuncSetAttribute((const void*)attn_gate_v1,
                        hipFuncAttributeMaxDynamicSharedMemorySize, (int)shmem);
    attn_gate_v1<<<NR / QBLK, 256, shmem, stream>>>(Np, gw, gwb, gb, ws, out);
  } else {
    const size_t shmem = (size_t)LDS0_SHORTS * sizeof(short);  // 113664 B
    hipFuncSetAttribute((const void*)attn_gate_v0,
                        hipFuncAttributeMaxDynamicSharedMemorySize, (int)shmem);
    attn_gate_v0<<<NR / QBLK, 256, shmem, stream>>>(Mp, Np, gw, gwb, gb, out);
  }
}